// Round 12
// baseline (172.452 us; speedup 1.0000x reference)
//
#include <hip/hip_runtime.h>
#include <hip/hip_bf16.h>
#include <cstdint>
#include <cstddef>

typedef unsigned short u16;
typedef __attribute__((ext_vector_type(8))) __bf16 bf16x8;
typedef __attribute__((ext_vector_type(4))) unsigned u32x4;
typedef __attribute__((ext_vector_type(16))) float f32x16;

#define LPOS 4096
#define CDIM 256
// per-buffer LDS (u16): 8192 K (32 rows x 256c) + 5120 V (4 planes x 160 rows x 8j)
#define LDSBUF 13312
// accumulator buffers: ref [2][156][4096] + src [2][5][4096] f32, atomically
// accumulated across j-chunks (replaces 41 MB chunked nsrc/nref round-trip)
#define RACC_N (2 * 156 * LPOS)
#define SACC_N (2 * 5 * LPOS)

#if __has_builtin(__builtin_amdgcn_exp2f)
#define EXP2(x) __builtin_amdgcn_exp2f(x)
#else
#define EXP2(x) exp2f(x)
#endif

// async global->LDS 16B: LDS dst must be wave-uniform base + lane*16
#define GLOAD_LDS16(g, l)                                                      \
  __builtin_amdgcn_global_load_lds(                                            \
      (const __attribute__((address_space(1))) void*)(g),                      \
      (__attribute__((address_space(3))) void*)(l), 16, 0, 0)

__device__ __forceinline__ unsigned f2bfbits(float x) {
  union { float f; unsigned u; } v; v.f = x;
  return (v.u + 0x7FFFu + ((v.u >> 16) & 1u)) >> 16;
}
__device__ __forceinline__ unsigned packbf(float a, float b) {
  __hip_bfloat162 h2 = __float22bfloat162_rn(make_float2(a, b));
  return *(unsigned*)&h2;
}

// ------- fused normalize: stats + normalize + transpose + bf16 cast --------
// Q (arr==0) is pre-scaled by log2(e): downstream uses exp2(Q.K) == exp(q.k).
__global__ void norm_fused(const float* __restrict__ t_in,
                           const float* __restrict__ s_in,
                           const float* __restrict__ r_in,
                           u16* __restrict__ qn, u16* __restrict__ ksn,
                           u16* __restrict__ krn) {
  __shared__ float tile[256 * 33];
  __shared__ float sums[256], sqs[256];
  __shared__ float mv[32], ivv[32];
  int idx = blockIdx.x;
  int ab = idx >> 7, lt = idx & 127;
  int arr = ab >> 1, b = ab & 1;
  int l0 = lt * 32;
  const float* inp = (arr == 0 ? t_in : arr == 1 ? s_in : r_in) + (size_t)b * CDIM * LPOS;
  u16* outp = (arr == 0 ? qn : arr == 1 ? ksn : krn) + (size_t)b * LPOS * CDIM;
  float scale = (arr == 0) ? 1.4426950408889634f : 1.0f;
  int t = threadIdx.x;
  int cg = t >> 5, l = t & 31;
  float sum = 0.f, sq = 0.f;
#pragma unroll 8
  for (int cc = 0; cc < 32; ++cc) {
    int c = cg * 32 + cc;
    float v = inp[(size_t)c * LPOS + l0 + l];
    tile[c * 33 + l] = v;
    sum += v; sq += v * v;
  }
  sums[t] = sum; sqs[t] = sq;
  __syncthreads();
  if (t < 32) {
    float s = 0.f, q = 0.f;
#pragma unroll
    for (int g = 0; g < 8; ++g) { s += sums[g * 32 + t]; q += sqs[g * 32 + t]; }
    float mean = s * (1.0f / CDIM);
    float nsq = q - s * s * (1.0f / CDIM);
    mv[t] = mean;
    ivv[t] = rsqrtf(fmaxf(nsq, 1e-20f)) * scale;
  }
  __syncthreads();
  int c2 = t & 127, ph = t >> 7;
#pragma unroll 4
  for (int rr = 0; rr < 16; ++rr) {
    int pos = ph + rr * 2;
    float m = mv[pos], iv = ivv[pos];
    float v0 = (tile[(2 * c2) * 33 + pos] - m) * iv;
    float v1 = (tile[(2 * c2 + 1) * 33 + pos] - m) * iv;
    *(unsigned*)&outp[(size_t)(l0 + pos) * CDIM + 2 * c2] = packbf(v0, v1);
  }
}

// ---------------- build combined V tensors + zero accumulators --------------
// vs: [2][32][4096]   ch: 0..3 src_feats, 4 ones, 5..31 zero
// vr: [2][160][4096]  ch: 0..150 sem, 151..154 ref_feats, 155 ones, 156..159 zero
// zacc: racc||sacc contiguous (1318912 f32) zeroed here - stream-ordered
// before flash's atomicAdd accumulation. Per-thread trivial write (no LDS,
// no occupancy interaction - avoids the R15 fusion trap).
__global__ void build_v(const float* __restrict__ sf, const float* __restrict__ rf,
                        const float* __restrict__ sem,
                        u16* __restrict__ vs, u16* __restrict__ vr,
                        float* __restrict__ zacc) {
  int t = blockIdx.x * 256 + threadIdx.x;
  if (t < RACC_N + SACC_N) zacc[t] = 0.0f;
  const int NVS = 2 * 32 * 4096;
  if (t < NVS) {
    int b = t >> 17;
    int c = (t >> 12) & 31;
    int j = t & 4095;
    float v = (c < 4) ? sf[((size_t)b * 4 + c) * LPOS + j] : (c == 4 ? 1.0f : 0.0f);
    vs[t] = (u16)f2bfbits(v);
  } else {
    int t2 = t - NVS;
    if (t2 < 2 * 160 * 4096) {
      int b = t2 / (160 * 4096);
      int rr = t2 % (160 * 4096);
      int c = rr >> 12, j = rr & 4095;
      float v = (c < 151) ? sem[((size_t)b * 151 + c) * LPOS + j]
              : (c < 155) ? rf[((size_t)b * 4 + (c - 151)) * LPOS + j]
              : (c == 155) ? 1.0f : 0.0f;
      vr[((size_t)b * 160 + c) * LPOS + j] = (u16)f2bfbits(v);
    }
  }
}

// ---------------- fused flash soft-warp ----------------
// S^T orientation: D[m=j][n=i] = sum_c K[j][c] * Q[i][c]
// PV: D[m=c][n=i]  = sum_j V[c][j] * P[j][i]
// R18: keep R17's verified 8-wave (512,2) structure (flash 59.0us, VGPR 120
// clean). Occupancy diagnosis: still 2 waves/SIMD - the unified VGPR+AGPR
// file (~200/wave: qf64 + acc80 + S-state) is the hard cap; wider needs QK
// duplication (negative EV). Change this round: epilogue writes become
// device-scope atomicAdd into small accumulators (racc/sacc) - kills the
// 41MB chunk-buffer write + 41MB finalize re-read.
template <int CT>
__device__ __forceinline__ void flash_body(
    const u16* __restrict__ qb, const u16* __restrict__ kb,
    const u16* __restrict__ vb, float* __restrict__ dst,
    u16 (*lds)[LDSBUF], int wave, int lane, int i_wave, int j_base, int iters) {
  int h = lane >> 5, ln = lane & 31;

  // Q fragments: B[k=c][n=i], lane n=ln, k = kt*16 + h*8 + t
  bf16x8 qf[16];
  const u16* qrow = qb + (size_t)(i_wave + ln) * CDIM;
#pragma unroll
  for (int kt = 0; kt < 16; ++kt)
    qf[kt] = *(const bf16x8*)(qrow + kt * 16 + h * 8);
  // pin: asm results cannot be rematerialized -> qf stays in VGPRs (R8)
#pragma unroll
  for (int kt = 0; kt < 16; ++kt)
    asm volatile("" : "+v"(*(u32x4*)&qf[kt]));

  f32x16 O[CT];
#pragma unroll
  for (int c = 0; c < CT; ++c)
#pragma unroll
    for (int t = 0; t < 16; ++t) O[c][t] = 0.0f;

  // Producer split across 8 waves: K 32 rows = 16 groups (2/wave); ref V =
  // 10 x 512-u16 slots (waves 0-1 take 2, waves 2-7 take 1).
  auto stage = [&](int j0s, int buf) {
#pragma unroll
    for (int g = 0; g < 2; ++g) {
      int G = wave * 2 + g;
      int j = 2 * G + h;
      GLOAD_LDS16(kb + (size_t)(j0s + j) * CDIM + (ln ^ (j & 7)) * 8,
                  &lds[buf][G * 512]);
    }
    if constexpr (CT == 5) {
#pragma unroll
      for (int g = 0; g < 2; ++g) {
        int s = wave + g * 8;               // 0..15, use 0..9
        if (s < 10) {
          int f = s * 64 + lane;            // flat 16B-chunk index 0..639
          int p = f / 160;                  // plane = j-octet
          int c = f - p * 160;              // V channel row
          GLOAD_LDS16(vb + (size_t)c * LPOS + j0s + p * 8,
                      &lds[buf][8192 + s * 512]);
        }
      }
    }
  };

  // Precomputed LDS read bases (buf 0); runtime bo = buf*LDSBUF added per read.
  int kread_base = ln * 256 + 8 * (h ^ (ln & 1));
  int q = (ln >> 1) & 3;
  const u16* ka[4];
#pragma unroll
  for (int m = 0; m < 4; ++m) ka[m] = &lds[0][kread_base + 16 * (m ^ q)];
  // V(ref) addr(kt2,ct,buf) = va + kt2*2560 + ct*256 + bo
  const u16* va = &lds[0][8192 + h * 1280 + ln * 8];

  // Deferred-softmax helper: exp/pack/PV for the PREVIOUS tile.
  f32x16 Sp;                // raw scores of tile jt-1 (pre-exp)
#pragma unroll
  for (int t = 0; t < 16; ++t) Sp[t] = 0.0f;

  auto finish_prev = [&](int pbo, const bf16x8* vfp) {
    f32x16 S;
#pragma unroll
    for (int t = 0; t < 16; ++t) S[t] = EXP2(Sp[t]);
    bf16x8 pb[2];
#pragma unroll
    for (int kh = 0; kh < 2; ++kh) {
      unsigned c0 = packbf(S[kh * 8 + 0], S[kh * 8 + 1]);
      unsigned c1 = packbf(S[kh * 8 + 2], S[kh * 8 + 3]);
      unsigned c2 = packbf(S[kh * 8 + 4], S[kh * 8 + 5]);
      unsigned c3 = packbf(S[kh * 8 + 6], S[kh * 8 + 7]);
      asm("v_permlane32_swap_b32 %0, %1" : "+v"(c0), "+v"(c2));
      asm("v_permlane32_swap_b32 %0, %1" : "+v"(c1), "+v"(c3));
      union { unsigned u[4]; bf16x8 v; } tmp;
      tmp.u[0] = c0;
      tmp.u[1] = c1;
      tmp.u[2] = c2;
      tmp.u[3] = c3;
      pb[kh] = tmp.v;
    }
#pragma unroll
    for (int ct = 0; ct < CT; ++ct)
#pragma unroll
      for (int kt2 = 0; kt2 < 2; ++kt2) {
        bf16x8 vax;
        if constexpr (CT == 5)
          vax = *(const bf16x8*)(va + kt2 * 2560 + ct * 256 + pbo);
        else
          vax = vfp[kt2];
        O[ct] = __builtin_amdgcn_mfma_f32_32x32x16_bf16(vax, pb[kt2], O[ct], 0, 0, 0);
      }
  };

  stage(j_base, 0);                  // depth-1 prefetch

  int buf = 0, pbo = 0;
  for (int jt = 0; jt < iters; ++jt) {
    int j0 = j_base + jt * 32;
    int bo = buf * LDSBUF;

    // Own stage(jt) is the only outstanding VM group at iter top.
    asm volatile("s_waitcnt vmcnt(0)" ::: "memory");
    __builtin_amdgcn_sched_barrier(0);
    __builtin_amdgcn_s_barrier();      // raw: no vmcnt/lgkm drain (8 waves)
    __builtin_amdgcn_sched_barrier(0);

    // src: V regs for the PREVIOUS tile (consumed by finish_prev this iter).
    // Issued BEFORE stage: compiler's wait for vf keeps prefetch in flight.
    bf16x8 vf[2];
    if (CT == 1 && jt >= 1) {
#pragma unroll
      for (int kt2 = 0; kt2 < 2; ++kt2)
        vf[kt2] = *(const bf16x8*)(vb + (size_t)ln * LPOS + (j0 - 32) + (2 * kt2 + h) * 8);
    }
    if (jt + 1 < iters) {
      int nb = (buf == 2) ? 0 : buf + 1;
      stage(j0 + 32, nb);              // producer LAST
    }

    __builtin_amdgcn_s_setprio(1);

    // QK(jt): A = K (LDS buf jt), B = Q (pinned regs)
    f32x16 Sa, Sb;
#pragma unroll
    for (int t = 0; t < 16; ++t) { Sa[t] = 0.0f; Sb[t] = 0.0f; }
#pragma unroll
    for (int kt = 0; kt < 16; kt += 2) {
      bf16x8 ka0 = *(const bf16x8*)(ka[kt & 3] + 64 * (kt >> 2) + bo);
      Sa = __builtin_amdgcn_mfma_f32_32x32x16_bf16(ka0, qf[kt], Sa, 0, 0, 0);
      bf16x8 ka1 = *(const bf16x8*)(ka[(kt + 1) & 3] + 64 * ((kt + 1) >> 2) + bo);
      Sb = __builtin_amdgcn_mfma_f32_32x32x16_bf16(ka1, qf[kt + 1], Sb, 0, 0, 0);
    }

    // finish tile jt-1 (independent of QK(jt) -> overlaps under MFMA issue)
    if (jt >= 1) finish_prev(pbo, vf);

    // hand off raw scores for next iter
#pragma unroll
    for (int t = 0; t < 16; ++t) Sp[t] = Sa[t] + Sb[t];

    __builtin_amdgcn_s_setprio(0);

    pbo = bo;
    buf = (buf == 2) ? 0 : buf + 1;
  }

  // tail: finish the last tile (its buffer is never overwritten post-loop)
  {
    bf16x8 vf[2];
    if constexpr (CT == 1) {
      int jlast = j_base + (iters - 1) * 32;
#pragma unroll
      for (int kt2 = 0; kt2 < 2; ++kt2)
        vf[kt2] = *(const bf16x8*)(vb + (size_t)ln * LPOS + jlast + (2 * kt2 + h) * 8);
    }
    finish_prev(pbo, vf);
  }

  // epilogue: atomicAdd into the (b-offset) accumulator; chunks sum in place.
  // ref: c<156 rows (151 sem + 4 feats + ones); src: c<5 (4 feats + ones).
  const int climit = (CT == 1) ? 5 : 156;
#pragma unroll
  for (int ct = 0; ct < CT; ++ct)
#pragma unroll
    for (int t = 0; t < 16; ++t) {
      int c = ct * 32 + (t & 3) + 8 * (t >> 2) + 4 * h;
      if (c < climit)
        atomicAdd(&dst[(size_t)c * LPOS + i_wave + ln], O[ct][t]);
    }
}

// 78 KB LDS, 512 threads (8 waves), (512,2): min 2 BLOCKS/CU (CUDA-semantics
// second arg, measured R16: (512,4) gave VGPR cap 64 = 4blk x 8w reading).
// VGPR cap 128 >= 120 measured clean (R17, flash 59.0us).
// Block order: ALL ref blocks first, then src (R13/R14: beats split AND
// forced interleave). Grid 512 = one full residency round.
__global__ __launch_bounds__(512, 2) void flash(
    const u16* __restrict__ qn, const u16* __restrict__ ksn, const u16* __restrict__ krn,
    const u16* __restrict__ vs, const u16* __restrict__ vr,
    float* __restrict__ sacc, float* __restrict__ racc,
    int nch_src, int nch_ref) {
  __shared__ u16 lds[3][LDSBUF];   // 78 KB
  int tid = threadIdx.x;
  int wave = tid >> 6, lane = tid & 63;
  int idx = blockIdx.x;
  int nrefb = 32 * nch_ref;
  // wave 0-3 -> rows i0+0..127; wave 4-7 -> rows i0+128..255
  int wsub = (wave & 3) * 32 + (wave >> 2) * 128;
  if (idx < nrefb) {                 // ref block (longest first)
    int r = idx;
    int chunk = r >> 5, b = (r >> 4) & 1, wgi = r & 15;
    int jchunk = LPOS / nch_ref;
    flash_body<5>(qn + (size_t)b * LPOS * CDIM, krn + (size_t)b * LPOS * CDIM,
                  vr + (size_t)b * 160 * LPOS,
                  racc + (size_t)b * 156 * LPOS,
                  lds, wave, lane, wgi * 256 + wsub, chunk * jchunk,
                  jchunk / 32);
  } else {                           // src block
    int r = idx - nrefb;
    int chunk = r >> 5, b = (r >> 4) & 1, wgi = r & 15;
    int jchunk = LPOS / nch_src;
    flash_body<1>(qn + (size_t)b * LPOS * CDIM, ksn + (size_t)b * LPOS * CDIM,
                  vs + (size_t)b * 32 * LPOS,
                  sacc + (size_t)b * 5 * LPOS,
                  lds, wave, lane, wgi * 256 + wsub, chunk * jchunk,
                  jchunk / 32);
  }
}

// ---------------- finalize: elementwise divide by ones-channel --------------
// Accumulation already done by flash's atomics: reads ~5.3 MB, writes 5.2 MB
// (was 41 MB read). float4-vectorized, 325632 v-outputs.
__global__ void finalize(const float* __restrict__ sacc, const float* __restrict__ racc,
                         float* __restrict__ out) {
  int v = blockIdx.x * 256 + threadIdx.x;
  if (v >= 325632) return;
  float4 n4, d4;
  if (v < 8192) {                         // warped_src_feat [2][4][4096]
    int b = v >> 12, c = (v >> 10) & 3, i4 = v & 1023;
    const float* base = sacc + (size_t)b * 5 * LPOS;
    n4 = ((const float4*)(base + (size_t)c * LPOS))[i4];
    d4 = ((const float4*)(base + (size_t)4 * LPOS))[i4];
  } else if (v < 16384) {                 // warped_ref_feat [2][4][4096]
    int v1 = v - 8192;
    int b = v1 >> 12, c = (v1 >> 10) & 3, i4 = v1 & 1023;
    const float* base = racc + (size_t)b * 156 * LPOS;
    n4 = ((const float4*)(base + (size_t)(151 + c) * LPOS))[i4];
    d4 = ((const float4*)(base + (size_t)155 * LPOS))[i4];
  } else {                                // warped_ref_seg [2][151][4096]
    int v2 = v - 16384;
    int b = v2 / 154624;                  // 151 * 1024
    int rr = v2 - b * 154624;
    int c = rr >> 10, i4 = rr & 1023;
    const float* base = racc + (size_t)b * 156 * LPOS;
    n4 = ((const float4*)(base + (size_t)c * LPOS))[i4];
    d4 = ((const float4*)(base + (size_t)155 * LPOS))[i4];
  }
  float4 r;
  r.x = n4.x / d4.x; r.y = n4.y / d4.y; r.z = n4.z / d4.z; r.w = n4.w / d4.w;
  ((float4*)out)[v] = r;
}

extern "C" void kernel_launch(void* const* d_in, const int* in_sizes, int n_in,
                              void* d_out, int out_size, void* d_ws, size_t ws_size,
                              hipStream_t stream) {
  const float* trg  = (const float*)d_in[0];
  const float* srcp = (const float*)d_in[1];
  const float* refp = (const float*)d_in[2];
  const float* sfeat = (const float*)d_in[3];
  const float* rfeat = (const float*)d_in[4];
  const float* rsem  = (const float*)d_in[5];
  float* out = (float*)d_out;

  char* ws = (char*)d_ws;
  size_t o = 0;
  auto alloc = [&](size_t bytes) -> char* {
    char* p = ws + o;
    o += (bytes + 255) & ~(size_t)255;
    return p;
  };
  u16* qn  = (u16*)alloc(2ull * LPOS * CDIM * 2);
  u16* ksn = (u16*)alloc(2ull * LPOS * CDIM * 2);
  u16* krn = (u16*)alloc(2ull * LPOS * CDIM * 2);
  u16* vs  = (u16*)alloc(2ull * 32 * LPOS * 2);
  u16* vr  = (u16*)alloc(2ull * 160 * LPOS * 2);
  // racc||sacc contiguous (zeroed by build_v, accumulated by flash atomics)
  float* racc = (float*)alloc((size_t)(RACC_N + SACC_N) * 4);
  float* sacc = racc + RACC_N;

  int nch_ref = 8;                       // j-split granularity (grid geometry
  int nch_src = 8;                       // only; accumulation is atomic now)

  hipLaunchKernelGGL(norm_fused, dim3(768), dim3(256), 0, stream,
                     trg, srcp, refp, qn, ksn, krn);
  hipLaunchKernelGGL(build_v, dim3(6144), dim3(256), 0, stream,
                     sfeat, rfeat, rsem, vs, vr, racc);
  hipLaunchKernelGGL(flash, dim3(32 * (nch_ref + nch_src)), dim3(512), 0, stream,
                     qn, ksn, krn, vs, vr, sacc, racc, nch_src, nch_ref);
  hipLaunchKernelGGL(finalize, dim3(1272), dim3(256), 0, stream,
                     sacc, racc, out);
}

// Round 13
// 146.193 us; speedup vs baseline: 1.1796x; 1.1796x over previous
//
#include <hip/hip_runtime.h>
#include <hip/hip_bf16.h>
#include <cstdint>
#include <cstddef>

typedef unsigned short u16;
typedef __attribute__((ext_vector_type(8))) __bf16 bf16x8;
typedef __attribute__((ext_vector_type(4))) unsigned u32x4;
typedef __attribute__((ext_vector_type(16))) float f32x16;

#define LPOS 4096
#define CDIM 256
// per-buffer LDS (u16): 8192 K (32 rows x 256c) + 5120 V (4 planes x 160 rows x 8j)
#define LDSBUF 13312

#if __has_builtin(__builtin_amdgcn_exp2f)
#define EXP2(x) __builtin_amdgcn_exp2f(x)
#else
#define EXP2(x) exp2f(x)
#endif

// async global->LDS 16B: LDS dst must be wave-uniform base + lane*16
#define GLOAD_LDS16(g, l)                                                      \
  __builtin_amdgcn_global_load_lds(                                            \
      (const __attribute__((address_space(1))) void*)(g),                      \
      (__attribute__((address_space(3))) void*)(l), 16, 0, 0)

__device__ __forceinline__ unsigned f2bfbits(float x) {
  union { float f; unsigned u; } v; v.f = x;
  return (v.u + 0x7FFFu + ((v.u >> 16) & 1u)) >> 16;
}
__device__ __forceinline__ unsigned packbf(float a, float b) {
  __hip_bfloat162 h2 = __float22bfloat162_rn(make_float2(a, b));
  return *(unsigned*)&h2;
}

// ------- fused normalize: stats + normalize + transpose + bf16 cast --------
// Q (arr==0) is pre-scaled by log2(e): downstream uses exp2(Q.K) == exp(q.k).
__global__ void norm_fused(const float* __restrict__ t_in,
                           const float* __restrict__ s_in,
                           const float* __restrict__ r_in,
                           u16* __restrict__ qn, u16* __restrict__ ksn,
                           u16* __restrict__ krn) {
  __shared__ float tile[256 * 33];
  __shared__ float sums[256], sqs[256];
  __shared__ float mv[32], ivv[32];
  int idx = blockIdx.x;
  int ab = idx >> 7, lt = idx & 127;
  int arr = ab >> 1, b = ab & 1;
  int l0 = lt * 32;
  const float* inp = (arr == 0 ? t_in : arr == 1 ? s_in : r_in) + (size_t)b * CDIM * LPOS;
  u16* outp = (arr == 0 ? qn : arr == 1 ? ksn : krn) + (size_t)b * LPOS * CDIM;
  float scale = (arr == 0) ? 1.4426950408889634f : 1.0f;
  int t = threadIdx.x;
  int cg = t >> 5, l = t & 31;
  float sum = 0.f, sq = 0.f;
#pragma unroll 8
  for (int cc = 0; cc < 32; ++cc) {
    int c = cg * 32 + cc;
    float v = inp[(size_t)c * LPOS + l0 + l];
    tile[c * 33 + l] = v;
    sum += v; sq += v * v;
  }
  sums[t] = sum; sqs[t] = sq;
  __syncthreads();
  if (t < 32) {
    float s = 0.f, q = 0.f;
#pragma unroll
    for (int g = 0; g < 8; ++g) { s += sums[g * 32 + t]; q += sqs[g * 32 + t]; }
    float mean = s * (1.0f / CDIM);
    float nsq = q - s * s * (1.0f / CDIM);
    mv[t] = mean;
    ivv[t] = rsqrtf(fmaxf(nsq, 1e-20f)) * scale;
  }
  __syncthreads();
  int c2 = t & 127, ph = t >> 7;
#pragma unroll 4
  for (int rr = 0; rr < 16; ++rr) {
    int pos = ph + rr * 2;
    float m = mv[pos], iv = ivv[pos];
    float v0 = (tile[(2 * c2) * 33 + pos] - m) * iv;
    float v1 = (tile[(2 * c2 + 1) * 33 + pos] - m) * iv;
    *(unsigned*)&outp[(size_t)(l0 + pos) * CDIM + 2 * c2] = packbf(v0, v1);
  }
}

// ---------------- build combined V tensors (bf16, [C_v][L]) -----------------
// vs: [2][32][4096]   ch: 0..3 src_feats, 4 ones, 5..31 zero
// vr: [2][160][4096]  ch: 0..150 sem, 151..154 ref_feats, 155 ones, 156..159 zero
__global__ void build_v(const float* __restrict__ sf, const float* __restrict__ rf,
                        const float* __restrict__ sem,
                        u16* __restrict__ vs, u16* __restrict__ vr) {
  int t = blockIdx.x * 256 + threadIdx.x;
  const int NVS = 2 * 32 * 4096;
  if (t < NVS) {
    int b = t >> 17;
    int c = (t >> 12) & 31;
    int j = t & 4095;
    float v = (c < 4) ? sf[((size_t)b * 4 + c) * LPOS + j] : (c == 4 ? 1.0f : 0.0f);
    vs[t] = (u16)f2bfbits(v);
  } else {
    int t2 = t - NVS;
    if (t2 < 2 * 160 * 4096) {
      int b = t2 / (160 * 4096);
      int rr = t2 % (160 * 4096);
      int c = rr >> 12, j = rr & 4095;
      float v = (c < 151) ? sem[((size_t)b * 151 + c) * LPOS + j]
              : (c < 155) ? rf[((size_t)b * 4 + (c - 151)) * LPOS + j]
              : (c == 155) ? 1.0f : 0.0f;
      vr[((size_t)b * 160 + c) * LPOS + j] = (u16)f2bfbits(v);
    }
  }
}

// ---------------- fused flash soft-warp (R17 config — session best) --------
// S^T orientation: D[m=j][n=i] = sum_c K[j][c] * Q[i][c]
// PV: D[m=c][n=i]  = sum_j V[c][j] * P[j][i]
// R19 = exact revert to R17 (flash 59.0us, VGPR 120 clean). R18's atomicAdd
// epilogue REGRESSED (94us): atomics write through the SAME 41MB (WRITE_SIZE
// unchanged) and 8 same-address adds/location serialize at L2 (~35us stall).
// Flash floor diagnosis (final): unified VGPR+AGPR file ~200 regs/wave
// (qf64 + acc80 + S-state) caps residency at 2 waves/SIMD; all pipes <=32%;
// widening requires QK duplication (negative EV). Verified wins kept:
// LPT packing (R11), deferred softmax (R12), 8-wave blocks + correct
// launch-bounds semantics (R17: 2nd arg = min BLOCKS/CU, measured R16).
template <int CT>
__device__ __forceinline__ void flash_body(
    const u16* __restrict__ qb, const u16* __restrict__ kb,
    const u16* __restrict__ vb, float* __restrict__ dst,
    u16 (*lds)[LDSBUF], int wave, int lane, int i_wave, int j_base, int iters) {
  int h = lane >> 5, ln = lane & 31;

  // Q fragments: B[k=c][n=i], lane n=ln, k = kt*16 + h*8 + t
  bf16x8 qf[16];
  const u16* qrow = qb + (size_t)(i_wave + ln) * CDIM;
#pragma unroll
  for (int kt = 0; kt < 16; ++kt)
    qf[kt] = *(const bf16x8*)(qrow + kt * 16 + h * 8);
  // pin: asm results cannot be rematerialized -> qf stays in VGPRs (R8)
#pragma unroll
  for (int kt = 0; kt < 16; ++kt)
    asm volatile("" : "+v"(*(u32x4*)&qf[kt]));

  f32x16 O[CT];
#pragma unroll
  for (int c = 0; c < CT; ++c)
#pragma unroll
    for (int t = 0; t < 16; ++t) O[c][t] = 0.0f;

  // Producer split across 8 waves: K 32 rows = 16 groups (2/wave); ref V =
  // 10 x 512-u16 slots (waves 0-1 take 2, waves 2-7 take 1).
  auto stage = [&](int j0s, int buf) {
#pragma unroll
    for (int g = 0; g < 2; ++g) {
      int G = wave * 2 + g;
      int j = 2 * G + h;
      GLOAD_LDS16(kb + (size_t)(j0s + j) * CDIM + (ln ^ (j & 7)) * 8,
                  &lds[buf][G * 512]);
    }
    if constexpr (CT == 5) {
#pragma unroll
      for (int g = 0; g < 2; ++g) {
        int s = wave + g * 8;               // 0..15, use 0..9
        if (s < 10) {
          int f = s * 64 + lane;            // flat 16B-chunk index 0..639
          int p = f / 160;                  // plane = j-octet
          int c = f - p * 160;              // V channel row
          GLOAD_LDS16(vb + (size_t)c * LPOS + j0s + p * 8,
                      &lds[buf][8192 + s * 512]);
        }
      }
    }
  };

  // Precomputed LDS read bases (buf 0); runtime bo = buf*LDSBUF added per read.
  int kread_base = ln * 256 + 8 * (h ^ (ln & 1));
  int q = (ln >> 1) & 3;
  const u16* ka[4];
#pragma unroll
  for (int m = 0; m < 4; ++m) ka[m] = &lds[0][kread_base + 16 * (m ^ q)];
  // V(ref) addr(kt2,ct,buf) = va + kt2*2560 + ct*256 + bo
  const u16* va = &lds[0][8192 + h * 1280 + ln * 8];

  // Deferred-softmax helper: exp/pack/PV for the PREVIOUS tile.
  f32x16 Sp;                // raw scores of tile jt-1 (pre-exp)
#pragma unroll
  for (int t = 0; t < 16; ++t) Sp[t] = 0.0f;

  auto finish_prev = [&](int pbo, const bf16x8* vfp) {
    f32x16 S;
#pragma unroll
    for (int t = 0; t < 16; ++t) S[t] = EXP2(Sp[t]);
    bf16x8 pb[2];
#pragma unroll
    for (int kh = 0; kh < 2; ++kh) {
      unsigned c0 = packbf(S[kh * 8 + 0], S[kh * 8 + 1]);
      unsigned c1 = packbf(S[kh * 8 + 2], S[kh * 8 + 3]);
      unsigned c2 = packbf(S[kh * 8 + 4], S[kh * 8 + 5]);
      unsigned c3 = packbf(S[kh * 8 + 6], S[kh * 8 + 7]);
      asm("v_permlane32_swap_b32 %0, %1" : "+v"(c0), "+v"(c2));
      asm("v_permlane32_swap_b32 %0, %1" : "+v"(c1), "+v"(c3));
      union { unsigned u[4]; bf16x8 v; } tmp;
      tmp.u[0] = c0;
      tmp.u[1] = c1;
      tmp.u[2] = c2;
      tmp.u[3] = c3;
      pb[kh] = tmp.v;
    }
#pragma unroll
    for (int ct = 0; ct < CT; ++ct)
#pragma unroll
      for (int kt2 = 0; kt2 < 2; ++kt2) {
        bf16x8 vax;
        if constexpr (CT == 5)
          vax = *(const bf16x8*)(va + kt2 * 2560 + ct * 256 + pbo);
        else
          vax = vfp[kt2];
        O[ct] = __builtin_amdgcn_mfma_f32_32x32x16_bf16(vax, pb[kt2], O[ct], 0, 0, 0);
      }
  };

  stage(j_base, 0);                  // depth-1 prefetch

  int buf = 0, pbo = 0;
  for (int jt = 0; jt < iters; ++jt) {
    int j0 = j_base + jt * 32;
    int bo = buf * LDSBUF;

    // Own stage(jt) is the only outstanding VM group at iter top.
    asm volatile("s_waitcnt vmcnt(0)" ::: "memory");
    __builtin_amdgcn_sched_barrier(0);
    __builtin_amdgcn_s_barrier();      // raw: no vmcnt/lgkm drain (8 waves)
    __builtin_amdgcn_sched_barrier(0);

    // src: V regs for the PREVIOUS tile (consumed by finish_prev this iter).
    // Issued BEFORE stage: compiler's wait for vf keeps prefetch in flight.
    bf16x8 vf[2];
    if (CT == 1 && jt >= 1) {
#pragma unroll
      for (int kt2 = 0; kt2 < 2; ++kt2)
        vf[kt2] = *(const bf16x8*)(vb + (size_t)ln * LPOS + (j0 - 32) + (2 * kt2 + h) * 8);
    }
    if (jt + 1 < iters) {
      int nb = (buf == 2) ? 0 : buf + 1;
      stage(j0 + 32, nb);              // producer LAST
    }

    __builtin_amdgcn_s_setprio(1);

    // QK(jt): A = K (LDS buf jt), B = Q (pinned regs)
    f32x16 Sa, Sb;
#pragma unroll
    for (int t = 0; t < 16; ++t) { Sa[t] = 0.0f; Sb[t] = 0.0f; }
#pragma unroll
    for (int kt = 0; kt < 16; kt += 2) {
      bf16x8 ka0 = *(const bf16x8*)(ka[kt & 3] + 64 * (kt >> 2) + bo);
      Sa = __builtin_amdgcn_mfma_f32_32x32x16_bf16(ka0, qf[kt], Sa, 0, 0, 0);
      bf16x8 ka1 = *(const bf16x8*)(ka[(kt + 1) & 3] + 64 * ((kt + 1) >> 2) + bo);
      Sb = __builtin_amdgcn_mfma_f32_32x32x16_bf16(ka1, qf[kt + 1], Sb, 0, 0, 0);
    }

    // finish tile jt-1 (independent of QK(jt) -> overlaps under MFMA issue)
    if (jt >= 1) finish_prev(pbo, vf);

    // hand off raw scores for next iter
#pragma unroll
    for (int t = 0; t < 16; ++t) Sp[t] = Sa[t] + Sb[t];

    __builtin_amdgcn_s_setprio(0);

    pbo = bo;
    buf = (buf == 2) ? 0 : buf + 1;
  }

  // tail: finish the last tile (its buffer is never overwritten post-loop)
  {
    bf16x8 vf[2];
    if constexpr (CT == 1) {
      int jlast = j_base + (iters - 1) * 32;
#pragma unroll
      for (int kt2 = 0; kt2 < 2; ++kt2)
        vf[kt2] = *(const bf16x8*)(vb + (size_t)ln * LPOS + jlast + (2 * kt2 + h) * 8);
    }
    finish_prev(pbo, vf);
  }

  // epilogue: D rows = c, cols = i. Trim never-read channels:
  // src uses c<5 (4 feats + ones), ref uses c<156 (151 sem + 4 feats + ones).
  const int climit = (CT == 1) ? 5 : 156;
#pragma unroll
  for (int ct = 0; ct < CT; ++ct)
#pragma unroll
    for (int t = 0; t < 16; ++t) {
      int c = ct * 32 + (t & 3) + 8 * (t >> 2) + 4 * h;
      if (c < climit)
        dst[(size_t)c * LPOS + i_wave + ln] = O[ct][t];
    }
}

// 78 KB LDS, 512 threads (8 waves), (512,2): min 2 BLOCKS/CU (CUDA-semantics
// second arg, measured R16: (512,4) gave VGPR cap 64 = 4blk x 8w reading).
// 2 blocks x 8 waves = 16 waves/CU; VGPR cap 128 >= 120 measured clean.
// Block order: ALL ref blocks first, then src (R13/R14: beats split AND
// forced interleave). Grid 512 = one full residency round.
__global__ __launch_bounds__(512, 2) void flash(
    const u16* __restrict__ qn, const u16* __restrict__ ksn, const u16* __restrict__ krn,
    const u16* __restrict__ vs, const u16* __restrict__ vr,
    float* __restrict__ nsrc, float* __restrict__ nref,
    int nch_src, int nch_ref) {
  __shared__ u16 lds[3][LDSBUF];   // 78 KB
  int tid = threadIdx.x;
  int wave = tid >> 6, lane = tid & 63;
  int idx = blockIdx.x;
  int nrefb = 32 * nch_ref;
  // wave 0-3 -> rows i0+0..127; wave 4-7 -> rows i0+128..255
  int wsub = (wave & 3) * 32 + (wave >> 2) * 128;
  if (idx < nrefb) {                 // ref block (longest first)
    int r = idx;
    int chunk = r >> 5, b = (r >> 4) & 1, wgi = r & 15;
    int jchunk = LPOS / nch_ref;
    flash_body<5>(qn + (size_t)b * LPOS * CDIM, krn + (size_t)b * LPOS * CDIM,
                  vr + (size_t)b * 160 * LPOS,
                  nref + (size_t)(chunk * 2 + b) * 160 * LPOS,
                  lds, wave, lane, wgi * 256 + wsub, chunk * jchunk,
                  jchunk / 32);
  } else {                           // src block
    int r = idx - nrefb;
    int chunk = r >> 5, b = (r >> 4) & 1, wgi = r & 15;
    int jchunk = LPOS / nch_src;
    flash_body<1>(qn + (size_t)b * LPOS * CDIM, ksn + (size_t)b * LPOS * CDIM,
                  vs + (size_t)b * 32 * LPOS,
                  nsrc + (size_t)(chunk * 2 + b) * 32 * LPOS,
                  lds, wave, lane, wgi * 256 + wsub, chunk * jchunk,
                  jchunk / 32);
  }
}

// ---------------- finalize: sum chunks, divide by ones-channel --------------
// float4-vectorized: 325632 float4 outputs (= 1302528 f32).
__global__ void finalize(const float* __restrict__ nsrc, const float* __restrict__ nref,
                         float* __restrict__ out, int nch_src, int nch_ref) {
  int v = blockIdx.x * 256 + threadIdx.x;
  if (v >= 325632) return;
  float nx = 0.f, ny = 0.f, nz = 0.f, nw = 0.f;
  float dx = 0.f, dy = 0.f, dz = 0.f, dw = 0.f;
  if (v < 8192) {                         // warped_src_feat [2][4][4096]
    int b = v >> 12, c = (v >> 10) & 3, i4 = v & 1023;
    for (int k = 0; k < nch_src; ++k) {
      const float* base = nsrc + ((size_t)(k * 2 + b) * 32) * LPOS;
      float4 n4 = ((const float4*)(base + (size_t)c * LPOS))[i4];
      float4 d4 = ((const float4*)(base + (size_t)4 * LPOS))[i4];
      nx += n4.x; ny += n4.y; nz += n4.z; nw += n4.w;
      dx += d4.x; dy += d4.y; dz += d4.z; dw += d4.w;
    }
  } else if (v < 16384) {                 // warped_ref_feat [2][4][4096]
    int v1 = v - 8192;
    int b = v1 >> 12, c = (v1 >> 10) & 3, i4 = v1 & 1023;
    for (int k = 0; k < nch_ref; ++k) {
      const float* base = nref + ((size_t)(k * 2 + b) * 160) * LPOS;
      float4 n4 = ((const float4*)(base + (size_t)(151 + c) * LPOS))[i4];
      float4 d4 = ((const float4*)(base + (size_t)155 * LPOS))[i4];
      nx += n4.x; ny += n4.y; nz += n4.z; nw += n4.w;
      dx += d4.x; dy += d4.y; dz += d4.z; dw += d4.w;
    }
  } else {                                // warped_ref_seg [2][151][4096]
    int v2 = v - 16384;
    int b = v2 / 154624;                  // 151 * 1024
    int rr = v2 - b * 154624;
    int c = rr >> 10, i4 = rr & 1023;
    for (int k = 0; k < nch_ref; ++k) {
      const float* base = nref + ((size_t)(k * 2 + b) * 160) * LPOS;
      float4 n4 = ((const float4*)(base + (size_t)c * LPOS))[i4];
      float4 d4 = ((const float4*)(base + (size_t)155 * LPOS))[i4];
      nx += n4.x; ny += n4.y; nz += n4.z; nw += n4.w;
      dx += d4.x; dy += d4.y; dz += d4.z; dw += d4.w;
    }
  }
  float4 r;
  r.x = nx / dx; r.y = ny / dy; r.z = nz / dz; r.w = nw / dw;
  ((float4*)out)[v] = r;
}

extern "C" void kernel_launch(void* const* d_in, const int* in_sizes, int n_in,
                              void* d_out, int out_size, void* d_ws, size_t ws_size,
                              hipStream_t stream) {
  const float* trg  = (const float*)d_in[0];
  const float* srcp = (const float*)d_in[1];
  const float* refp = (const float*)d_in[2];
  const float* sfeat = (const float*)d_in[3];
  const float* rfeat = (const float*)d_in[4];
  const float* rsem  = (const float*)d_in[5];
  float* out = (float*)d_out;

  char* ws = (char*)d_ws;
  size_t o = 0;
  auto alloc = [&](size_t bytes) -> char* {
    char* p = ws + o;
    o += (bytes + 255) & ~(size_t)255;
    return p;
  };
  u16* qn  = (u16*)alloc(2ull * LPOS * CDIM * 2);
  u16* ksn = (u16*)alloc(2ull * LPOS * CDIM * 2);
  u16* krn = (u16*)alloc(2ull * LPOS * CDIM * 2);
  u16* vs  = (u16*)alloc(2ull * 32 * LPOS * 2);
  u16* vr  = (u16*)alloc(2ull * 160 * LPOS * 2);

  size_t fixed = o;
  int nch_ref = 8;                       // nch_src = nch_ref (uniform blocks)
  for (;;) {
    size_t need = fixed + 512 +
                  (size_t)nch_ref * 2 * 32 * LPOS * 4 +
                  (size_t)nch_ref * 2 * 160 * LPOS * 4;
    if (need <= ws_size || nch_ref == 1) break;
    nch_ref >>= 1;
  }
  int nch_src = nch_ref;
  float* nsrc = (float*)alloc((size_t)nch_src * 2 * 32 * LPOS * 4);
  float* nref = (float*)alloc((size_t)nch_ref * 2 * 160 * LPOS * 4);

  hipLaunchKernelGGL(norm_fused, dim3(768), dim3(256), 0, stream,
                     trg, srcp, refp, qn, ksn, krn);
  hipLaunchKernelGGL(build_v, dim3(6144), dim3(256), 0, stream,
                     sfeat, rfeat, rsem, vs, vr);
  hipLaunchKernelGGL(flash, dim3(32 * (nch_ref + nch_src)), dim3(512), 0, stream,
                     qn, ksn, krn, vs, vr, nsrc, nref, nch_src, nch_ref);
  hipLaunchKernelGGL(finalize, dim3(1272), dim3(256), 0, stream,
                     nsrc, nref, out, nch_src, nch_ref);
}